// Round 3
// baseline (46.617 us; speedup 1.0000x reference)
//
#include <hip/hip_runtime.h>

// GraphProjection on MI355X (gfx950).
// x:(8,512,64,64) f32, anchor/sigma:(128,512) f32.
// d_out = nodes (8,512,128) ++ soft_assign (8,128,256).
//
// gp_prep:   rs=1/sigma, ars=anchor/sigma table [g][c][16] for scalar loads.
// gp_logits: streaming pass 1 (no LDS in hot loop, no barriers): lane=pixel,
//            iterate channels; per-wave-uniform anc rows -> s_load; softmax at
//            the end via one LDS combine. Writes soft_assign.
// gp_accum:  pass 2 with double-buffered global_load_lds pipeline (raw
//            s_barrier + counted vmcnt so loads stay in flight across barriers).
//            Writes raw S1 partials to ws.
// gp_final:  combine parts, S0 from soft_assign, normalize, transposed store.

#define NCH 512

typedef __attribute__((address_space(3))) void lds_void_t;
typedef const __attribute__((address_space(1))) void gbl_void_t;

__device__ __forceinline__ void gload_lds16(const float* g, float* l) {
  __builtin_amdgcn_global_load_lds((gbl_void_t*)g, (lds_void_t*)l, 16, 0, 0);
}

// ---------------------------------------------------------------- prep
__global__ __launch_bounds__(512, 2)
void gp_prep(const float* __restrict__ anchor,
             const float* __restrict__ sigma,
             float* __restrict__ ws_anc) {   // [16][512][16]
  const int g = blockIdx.x;    // 0..15
  const int c = threadIdx.x;   // 0..511
  float vals[16];
#pragma unroll
  for (int k = 0; k < 8; ++k) {
    float a = anchor[((g << 3) + k) * NCH + c];
    float s = sigma [((g << 3) + k) * NCH + c];
    float r = 1.0f / s;
    vals[k]     = r;
    vals[k + 8] = a * r;
  }
  float4* dst = (float4*)(ws_anc + (((size_t)g * NCH + c) << 4));
#pragma unroll
  for (int q = 0; q < 4; ++q) dst[q] = ((float4*)vals)[q];
}

// ---------------------------------------------------------------- pass 1
__global__ __launch_bounds__(512, 2)
void gp_logits(const float* __restrict__ x,
               const float* __restrict__ ws_anc,
               float* __restrict__ soft_out) {
  __shared__ float sc[8 * 64 * 8];   // [wave][px][k] 16 KB
  const int tid = threadIdx.x;
  const int bid = blockIdx.x;        // = gx*128 + (b*16 + gy*4 + q)
  const int gx = bid >> 7;
  const int r  = bid & 127;
  const int q  = r & 3;
  const int gy = (r >> 2) & 3;
  const int b  = r >> 4;
  const int g  = (gy << 2) + gx;
  const int w  = __builtin_amdgcn_readfirstlane(tid >> 6);  // wave-uniform c-eighth
  const int lane = tid & 63;
  const int prow = lane >> 4, pcol = lane & 15;
  const int y = (gy << 4) + (q << 2) + prow;

  const float* xp = x + (size_t)b * (NCH * 4096)
                      + (size_t)(w << 6) * 4096 + y * 64 + (gx << 4) + pcol;
  const float4* ap = (const float4*)(ws_anc + (((size_t)g * NCH + (w << 6)) << 4));

  float sq[8];
#pragma unroll
  for (int k = 0; k < 8; ++k) sq[k] = 0.0f;

#pragma unroll 8
  for (int cc = 0; cc < 64; ++cc) {
    float xv = xp[(size_t)cc * 4096];
    float4 r0 = ap[(cc << 2) + 0];
    float4 r1 = ap[(cc << 2) + 1];
    float4 a0 = ap[(cc << 2) + 2];
    float4 a1 = ap[(cc << 2) + 3];
    float t;
    t = fmaf(xv, r0.x, -a0.x); sq[0] = fmaf(t, t, sq[0]);
    t = fmaf(xv, r0.y, -a0.y); sq[1] = fmaf(t, t, sq[1]);
    t = fmaf(xv, r0.z, -a0.z); sq[2] = fmaf(t, t, sq[2]);
    t = fmaf(xv, r0.w, -a0.w); sq[3] = fmaf(t, t, sq[3]);
    t = fmaf(xv, r1.x, -a1.x); sq[4] = fmaf(t, t, sq[4]);
    t = fmaf(xv, r1.y, -a1.y); sq[5] = fmaf(t, t, sq[5]);
    t = fmaf(xv, r1.z, -a1.z); sq[6] = fmaf(t, t, sq[6]);
    t = fmaf(xv, r1.w, -a1.w); sq[7] = fmaf(t, t, sq[7]);
  }

  const int sbase = ((w << 6) + lane) << 3;
  *(float4*)&sc[sbase]     = make_float4(sq[0], sq[1], sq[2], sq[3]);
  *(float4*)&sc[sbase + 4] = make_float4(sq[4], sq[5], sq[6], sq[7]);
  __syncthreads();

  // combine 8 c-partials + softmax over nodes; thread = (px, k)
  {
    const int px = tid >> 3, k = tid & 7;
    float acc = 0.0f;
#pragma unroll
    for (int w2 = 0; w2 < 8; ++w2) acc += sc[(w2 << 9) + tid];  // conflict-free
    float l = -0.5f * acc;
    float mx = l;
    mx = fmaxf(mx, __shfl_xor(mx, 1, 64));
    mx = fmaxf(mx, __shfl_xor(mx, 2, 64));
    mx = fmaxf(mx, __shfl_xor(mx, 4, 64));
    float e = __expf(l - mx);
    float es = e;
    es += __shfl_xor(es, 1, 64);
    es += __shfl_xor(es, 2, 64);
    es += __shfl_xor(es, 4, 64);
    soft_out[(size_t)((b << 7) + (g << 3) + k) * 256 + (q << 6) + px] = e / es;
  }
}

// ---------------------------------------------------------------- pass 2
__global__ __launch_bounds__(512, 2)
void gp_accum(const float* __restrict__ x,
              const float* __restrict__ soft_in,
              float* __restrict__ ws_s1,
              int plog) {
  __shared__ float chunk[2][NCH * 16];   // 64 KB, quad-swizzled rows
  __shared__ float soft_lds[256 * 8];    // [pxp][k] (sized for plog=0)
  const int tid = threadIdx.x;
  const int bid = blockIdx.x;            // gx*(32<<plog) + (b*(4<<plog)+gy*(1<<plog)+part)
  const int parts = 1 << plog;
  const int gx = bid >> (5 + plog);
  const int r  = bid & ((32 << plog) - 1);
  const int part = r & (parts - 1);
  const int gy = (r >> plog) & 3;
  const int b  = r >> (plog + 2);
  const int g  = (gy << 2) + gx;
  const int nrows = 16 >> plog;
  const int npx   = nrows << 4;
  const int y0 = (gy << 4) + part * nrows;
  const int x0 = gx << 4;
  const float* xb = x + (size_t)b * (NCH * 4096);

  // soft -> LDS [pxp][k]
  for (int i = tid; i < npx * 8; i += 512) {
    int k   = i >> (8 - plog);
    int pxp = i & (npx - 1);
    soft_lds[(pxp << 3) + k] =
        soft_in[(size_t)((b << 7) + (g << 3) + k) * 256 + part * npx + pxp];
  }

  auto stage = [&](int buf, int row) {
#pragma unroll
    for (int it = 0; it < 4; ++it) {
      int flat = it * 512 + tid;
      int ci   = flat >> 2;
      int qd   = flat & 3;
      int qs   = qd ^ ((ci >> 1) & 3);
      const float* src = xb + (size_t)ci * 4096 + (y0 + row) * 64 + x0 + (qs << 2);
      gload_lds16(src, &chunk[buf][flat << 2]);
    }
  };

  float S1[8];
#pragma unroll
  for (int k = 0; k < 8; ++k) S1[k] = 0.0f;

  stage(0, 0);
  asm volatile("s_waitcnt lgkmcnt(0)" ::: "memory");  // soft_lds writes drained

  const int csw = (tid >> 1) & 3;
  for (int rr = 0; rr < nrows; ++rr) {
    const int cur = rr & 1;
    if (rr < nrows - 1) {
      stage(cur ^ 1, rr + 1);                       // next row in flight
      asm volatile("s_waitcnt vmcnt(4)" ::: "memory");  // current row landed
    } else {
      asm volatile("s_waitcnt vmcnt(0)" ::: "memory");
    }
    asm volatile("s_barrier" ::: "memory");          // raw: no vmcnt(0) drain

    const float* ch = &chunk[cur][tid << 4];
#pragma unroll
    for (int qd = 0; qd < 4; ++qd) {
      float4 xv = *(const float4*)(ch + ((qd ^ csw) << 2));
#pragma unroll
      for (int j = 0; j < 4; ++j) {
        float xvj = (j == 0) ? xv.x : (j == 1) ? xv.y : (j == 2) ? xv.z : xv.w;
        const float* sp = &soft_lds[((rr << 4) + (qd << 2) + j) << 3];
        float4 s0 = *(const float4*)sp;
        float4 s1 = *(const float4*)(sp + 4);
        S1[0] = fmaf(xvj, s0.x, S1[0]);
        S1[1] = fmaf(xvj, s0.y, S1[1]);
        S1[2] = fmaf(xvj, s0.z, S1[2]);
        S1[3] = fmaf(xvj, s0.w, S1[3]);
        S1[4] = fmaf(xvj, s1.x, S1[4]);
        S1[5] = fmaf(xvj, s1.y, S1[5]);
        S1[6] = fmaf(xvj, s1.z, S1[6]);
        S1[7] = fmaf(xvj, s1.w, S1[7]);
      }
    }
    asm volatile("s_barrier" ::: "memory");  // reads done before buf reuse
  }

  const int bg = (b << 4) + g;
  float* wp = ws_s1 + ((size_t)(bg * parts + part) << 3) * NCH + tid;
#pragma unroll
  for (int k = 0; k < 8; ++k) wp[k * NCH] = S1[k];
}

// ---------------------------------------------------------------- finalize
__global__ __launch_bounds__(512, 4)
void gp_final(const float* __restrict__ anchor,
              const float* __restrict__ sigma,
              const float* __restrict__ soft_out,
              const float* __restrict__ ws_s1,
              float* __restrict__ nodes_out,
              int parts) {
  const int bg = blockIdx.x;   // b*16+g
  const int b  = bg >> 4, g = bg & 15;
  const int tid = threadIdx.x; // channel c
  __shared__ float sS0[8];
  __shared__ float red[8 * 8];
  __shared__ float invn[8];

  if (tid < 256) {
    int k = tid >> 5, sl = tid & 31;
    const float* sp = soft_out + (size_t)((b << 7) + (g << 3) + k) * 256 + (sl << 3);
    float4 a0 = *(const float4*)sp;
    float4 a1 = *(const float4*)(sp + 4);
    float v = a0.x + a0.y + a0.z + a0.w + a1.x + a1.y + a1.z + a1.w;
    v += __shfl_xor(v, 1, 64);
    v += __shfl_xor(v, 2, 64);
    v += __shfl_xor(v, 4, 64);
    v += __shfl_xor(v, 8, 64);
    v += __shfl_xor(v, 16, 64);
    if (sl == 0) sS0[k] = v;
  }
  __syncthreads();

  float S1[8];
#pragma unroll
  for (int k = 0; k < 8; ++k) S1[k] = 0.0f;
  for (int pt = 0; pt < parts; ++pt) {
    const float* wp = ws_s1 + ((size_t)(bg * parts + pt) << 3) * NCH + tid;
#pragma unroll
    for (int k = 0; k < 8; ++k) S1[k] += wp[k * NCH];
  }

  float v[8];
#pragma unroll
  for (int k = 0; k < 8; ++k) {
    float s  = sigma [((g << 3) + k) * NCH + tid];
    float a  = anchor[((g << 3) + k) * NCH + tid];
    float rs = 1.0f / s;
    float S0 = sS0[k];
    float nd = rs * S1[k] - (a * rs) * S0;
    v[k] = nd / (S0 + 1e-9f);
  }

  const int wv = tid >> 6, lane = tid & 63;
#pragma unroll
  for (int k = 0; k < 8; ++k) {
    float s = v[k] * v[k];
    s += __shfl_xor(s, 1, 64);
    s += __shfl_xor(s, 2, 64);
    s += __shfl_xor(s, 4, 64);
    s += __shfl_xor(s, 8, 64);
    s += __shfl_xor(s, 16, 64);
    s += __shfl_xor(s, 32, 64);
    if (lane == 0) red[(wv << 3) + k] = s;
  }
  __syncthreads();
  if (tid < 8) {
    float t2 = 0.0f;
#pragma unroll
    for (int w = 0; w < 8; ++w) t2 += red[(w << 3) + tid];
    invn[tid] = 1.0f / fmaxf(sqrtf(t2), 1e-12f);
  }
  __syncthreads();

  float4 o0 = make_float4(v[0] * invn[0], v[1] * invn[1], v[2] * invn[2], v[3] * invn[3]);
  float4 o1 = make_float4(v[4] * invn[4], v[5] * invn[5], v[6] * invn[6], v[7] * invn[7]);
  float* dst = nodes_out + ((size_t)(b * NCH) + tid) * 128 + (g << 3);
  *(float4*)(dst)     = o0;
  *(float4*)(dst + 4) = o1;
}

extern "C" void kernel_launch(void* const* d_in, const int* in_sizes, int n_in,
                              void* d_out, int out_size, void* d_ws, size_t ws_size,
                              hipStream_t stream) {
  const float* x      = (const float*)d_in[0];
  const float* anchor = (const float*)d_in[1];
  const float* sigma  = (const float*)d_in[2];
  float* out = (float*)d_out;
  float* wsf = (float*)d_ws;

  const size_t n_nodes = 524288;           // 8*512*128
  float* soft_out = out + n_nodes;
  float* ws_anc = wsf;                     // 16*512*16 = 131072 floats
  float* ws_s1  = wsf + 131072;

  int plog;
  if      (ws_size >= (131072 + 4u * 524288) * sizeof(float)) plog = 2;
  else if (ws_size >= (131072 + 2u * 524288) * sizeof(float)) plog = 1;
  else                                                        plog = 0;

  gp_prep  <<<16,           512, 0, stream>>>(anchor, sigma, ws_anc);
  gp_logits<<<512,          512, 0, stream>>>(x, ws_anc, soft_out);
  gp_accum <<<128 << plog,  512, 0, stream>>>(x, soft_out, ws_s1, plog);
  gp_final <<<128,          512, 0, stream>>>(anchor, sigma, soft_out, ws_s1, out,
                                              1 << plog);
}